// Round 1
// baseline (908.233 us; speedup 1.0000x reference)
//
#include <hip/hip_runtime.h>
#include <hip/hip_bf16.h>

// VLLMKVCache: out = cache; out[block_indices[t], block_offset[t], :, :] = input[t, :, :]
// cache: (1024, 128, 8, 128) f32 -> token row = contiguous 1024 floats (4 KiB)
// input: (8192, 8, 128) f32    -> token row = contiguous 1024 floats (4 KiB)

__global__ void kv_scatter_kernel(const float* __restrict__ inp,
                                  float* __restrict__ out,
                                  const int* __restrict__ block_indices,
                                  const int* __restrict__ block_offset,
                                  int row_elems /*=1024*/,
                                  int block_size /*=128*/) {
    const int t = blockIdx.x;                 // token index
    const int bi = block_indices[t];
    const int bo = block_offset[t];
    // 256 threads x float4 = 1024 floats per token row
    const float4* __restrict__ src =
        (const float4*)(inp + (size_t)t * row_elems);
    float4* __restrict__ dst =
        (float4*)(out + ((size_t)bi * block_size + bo) * (size_t)row_elems);
    dst[threadIdx.x] = src[threadIdx.x];
}

extern "C" void kernel_launch(void* const* d_in, const int* in_sizes, int n_in,
                              void* d_out, int out_size, void* d_ws, size_t ws_size,
                              hipStream_t stream) {
    const float* inp          = (const float*)d_in[0];
    const float* cache        = (const float*)d_in[1];
    // d_in[2] = num_kv_cache_passes (scalar), d_in[3] = num_slots_available (scalar)
    const int*   block_indices = (const int*)d_in[4];
    const int*   block_offset  = (const int*)d_in[5];
    float* out = (float*)d_out;

    const int num_tokens = in_sizes[4];            // 8192
    const int row_elems  = in_sizes[0] / num_tokens; // 8*128 = 1024
    const int block_size = 128;                    // BLOCK_SIZE from reference

    // 1) Bulk copy cache -> out (512 MiB). D2D async memcpy is graph-capture safe
    //    and runs at near-peak HBM bandwidth.
    (void)hipMemcpyAsync(out, cache, (size_t)out_size * sizeof(float),
                         hipMemcpyDeviceToDevice, stream);

    // 2) Scatter the 8192 token rows (4 KiB each, fully contiguous & coalesced).
    //    One block per token, 256 threads x float4.
    kv_scatter_kernel<<<num_tokens, 256, 0, stream>>>(
        inp, out, block_indices, block_offset, row_elems, block_size);
}